// Round 14
// baseline (20.920 us; speedup 1.0000x reference)
//
#include <hip/hip_runtime.h>
#include <math.h>

#define N_BUS 127
#define BATCH 4096
#define NUM_CS 200
#define STATE_DIM 858   // 4 + 2*127 + 3*200
#define EV_START 258    // 4 + 2*127
#define COLS 8          // batch columns per block -> 512 blocks of 256 threads
#define NITER 3         // error ~7e-8 << bf16-K noise (~2e-4) << 0.03 margin

typedef __attribute__((ext_vector_type(8))) short short8;
typedef __attribute__((ext_vector_type(4))) short short4v;
typedef __attribute__((ext_vector_type(4))) float f32x4;

// RNE float -> bf16
static __device__ __forceinline__ short f2bf(float f) {
    unsigned u = __float_as_uint(f);
    return (short)((u + 0x7FFFu + ((u >> 16) & 1u)) >> 16);
}

// Precompute bf16 MFMA A-fragments of K (r3's verified layout).
// frag index: ((wt*4 + kt)*2 + p)*64 + lane, wt = row-tile 0..7:
//   row = 16*wt + (l&15), k = 32kt + 8*(l>>4) + i ; p=0 Re, p=1 Im.
__global__ __launch_bounds__(256) void prep_frags(const float2* __restrict__ K,
                                                  short8* __restrict__ frags) {
    int idx = blockIdx.x * 256 + threadIdx.x;   // 0..4095
    int l    = idx & 63;
    int rest = idx >> 6;
    int p  = rest & 1;
    int kt = (rest >> 1) & 3;
    int wt = rest >> 3;
    int row = 16 * wt + (l & 15);
    int k0  = 32 * kt + 8 * (l >> 4);
    short8 o;
    #pragma unroll
    for (int i = 0; i < 8; ++i) {
        float val = 0.0f;
        int k = k0 + i;
        if (row < N_BUS && k < N_BUS) {
            float2 e = K[row * N_BUS + k];
            val = p ? e.y : e.x;
        }
        o[i] = f2bf(val);
    }
    frags[idx] = o;
}

// 4 waves x 256 threads. Wave w owns rows [32w, 32w+32) as 2 M-tiles (t=0,1).
// MFMA 16x16x32 fragment roles (verified rounds 3-13):
//   A: row = 32w+16t + (l&15), k = 32kt + 8*(l>>4) + i
//   B: col = l&15,             k = 32kt + 8*(l>>4) + i
//   D: col = l&15,             row = 32w+16t + 4*(l>>4) + r
// Column slots 8..15 duplicate 0..7 (benign: MFMA columns are independent).
__global__ __launch_bounds__(256, 3) void vvl_main(const float* __restrict__ action,
                                                   const float* __restrict__ state,
                                                   const short8* __restrict__ frags,
                                                   const float2* __restrict__ Lp,
                                                   float* __restrict__ out) {
    __shared__ float sq[COLS][258];      // [col]: p (EV added in) then q
    __shared__ __align__(16) short B8s[2][2][4][4][16][8];  // lane-linear reads
    __shared__ float lossred[COLS];

    const int tid = threadIdx.x;
    const int w  = tid >> 6;         // wave 0..3 -> rows [32w, 32w+32)
    const int l  = tid & 63;
    const int cc = l & 15;           // B-column slot; data column = cc&7
    const int c8 = cc & 7;
    const int g  = l >> 4;           // lane group 0..3
    const int b0 = blockIdx.x * COLS;
    const int col = tid >> 5;        // prologue column mapping (32 thr/col)
    const int j   = tid & 31;

    const float*  st_row_c = state + (size_t)(b0 + col) * STATE_DIM;
    const float2* st2      = (const float2*)(st_row_c + 4);
    const float*  act_row  = action + (size_t)(b0 + col) * NUM_CS;

    // ======= issue all prologue loads before any use (in-order VMEM) =======
    // batch 1: p/q
    float2 pqv[4];
    #pragma unroll
    for (int jj = 0; jj < 4; ++jj) {
        int idx = j + 32 * jj; idx = idx < 127 ? idx : 126;
        pqv[jj] = st2[idx];
    }
    // batch 2: EV (21 scalars)
    float av[7], capv[7], busv[7];
    #pragma unroll
    for (int kk = 0; kk < 7; ++kk) {
        int cs = j + 32 * kk; int csc = cs < NUM_CS ? cs : NUM_CS - 1;
        av[kk]   = act_row[csc];
        capv[kk] = st_row_c[EV_START + 3 * csc];
        busv[kk] = st_row_c[EV_START + 2 + 3 * csc];
    }
    // batch 3: K A-fragments, coalesced 16B/lane (wt = 2w + t)
    short8 AKr[2][4], AKi[2][4];
    #pragma unroll
    for (int t = 0; t < 2; ++t)
        #pragma unroll
        for (int kt = 0; kt < 4; ++kt) {
            AKr[t][kt] = frags[(((2 * w + t) * 4 + kt) * 2 + 0) * 64 + l];
            AKi[t][kt] = frags[(((2 * w + t) * 4 + kt) * 2 + 1) * 64 + l];
        }

    if (tid < COLS) lossred[tid] = 0.0f;

    // ======= consume in issue order =======
    #pragma unroll
    for (int jj = 0; jj < 4; ++jj) {
        int idx = j + 32 * jj;
        if (idx < 127) *(float2*)&sq[col][2 * idx] = pqv[jj];
    }
    __syncthreads();

    // EV power + scatter-add into staged p
    #pragma unroll
    for (int kk = 0; kk < 7; ++kk) {
        int cs = j + 32 * kk;
        float cap  = capv[kk];
        float conn = (cap > 0.0f) ? 1.0f : 0.0f;
        float mch  = fminf(22.0f,  conn * (70.0f - cap) * 4.0f);  // /0.25 == *4
        float mds  = fmaxf(-22.0f, conn * (15.0f - cap) * 4.0f);
        float pw   = fmaxf(fminf(av[kk] * 22.17f, mch), mds);
        int bi = (int)busv[kk];
        bi = bi < 0 ? 0 : (bi > N_BUS - 1 ? N_BUS - 1 : bi);
        if (cs < NUM_CS) atomicAdd(&sq[col][bi], pw);
    }
    __syncthreads();   // sq final

    // ---- per-lane S/v state: 2 tiles x 4 rows of column c8 ----
    float Sr[2][4], Si[2][4], lmr[2][4], lmi[2][4], vr[2][4], vi[2][4];
    #pragma unroll
    for (int t = 0; t < 2; ++t)
        #pragma unroll
        for (int r = 0; r < 4; ++r) {
            int row = 32 * w + 16 * t + 4 * g + r;
            if (row < N_BUS) {
                Sr[t][r] = sq[c8][row] * 1e-3f;
                Si[t][r] = sq[c8][127 + row] * 1e-3f;
                float2 lp = Lp[row];
                lmr[t][r] = lp.x; lmi[t][r] = lp.y;
            } else {  // pad row 127: S=0 -> Lc=0; A col 127 is zero anyway
                Sr[t][r] = 0.0f; Si[t][r] = 0.0f; lmr[t][r] = 1.0f; lmi[t][r] = 0.0f;
            }
            vr[t][r] = 1.0f; vi[t][r] = 0.0f;
        }

    // ---- fixed-point loop: v = K @ conj(S/v) + L on matrix cores ----
    for (int it = 0; it < NITER; ++it) {
        const int buf = it & 1;
        #pragma unroll
        for (int t = 0; t < 2; ++t) {
            short4v pr, pi;
            #pragma unroll
            for (int r = 0; r < 4; ++r) {
                float d   = vr[t][r] * vr[t][r] + vi[t][r] * vi[t][r];
                float inv = __builtin_amdgcn_rcpf(d);
                pr[r] = f2bf((Sr[t][r] * vr[t][r] + Si[t][r] * vi[t][r]) * inv);
                pi[r] = f2bf((Sr[t][r] * vi[t][r] - Si[t][r] * vr[t][r]) * inv);
            }
            const int k0  = 32 * w + 16 * t + 4 * g;   // rows this lane owns
            const int ktw = k0 >> 5;
            const int gi  = (k0 >> 3) & 3;
            const int i0  = k0 & 7;
            *(short4v*)&B8s[buf][0][ktw][gi][cc][i0] = pr;
            *(short4v*)&B8s[buf][1][ktw][gi][cc][i0] = pi;
        }
        __syncthreads();   // single barrier/iter (4 waves); dbuf handles WAR

        f32x4 are[2], aim[2];
        #pragma unroll
        for (int t = 0; t < 2; ++t) {
            are[t] = f32x4{0.f, 0.f, 0.f, 0.f};
            aim[t] = f32x4{0.f, 0.f, 0.f, 0.f};
        }
        #pragma unroll
        for (int kt = 0; kt < 4; ++kt) {
            short8 Br  = *(const short8*)&B8s[buf][0][kt][g][cc][0];
            short8 Bi8 = *(const short8*)&B8s[buf][1][kt][g][cc][0];
            short8 Bin;
            #pragma unroll
            for (int i = 0; i < 8; ++i) Bin[i] = Bi8[i] ^ (short)0x8000;   // -Li
            #pragma unroll
            for (int t = 0; t < 2; ++t) {
                aim[t] = __builtin_amdgcn_mfma_f32_16x16x32_bf16(AKr[t][kt], Bi8, aim[t], 0, 0, 0);
                aim[t] = __builtin_amdgcn_mfma_f32_16x16x32_bf16(AKi[t][kt], Br,  aim[t], 0, 0, 0);
                are[t] = __builtin_amdgcn_mfma_f32_16x16x32_bf16(AKr[t][kt], Br,  are[t], 0, 0, 0);
                are[t] = __builtin_amdgcn_mfma_f32_16x16x32_bf16(AKi[t][kt], Bin, are[t], 0, 0, 0);
            }
        }
        #pragma unroll
        for (int t = 0; t < 2; ++t)
            #pragma unroll
            for (int r = 0; r < 4; ++r) {
                vr[t][r] = are[t][r] + lmr[t][r];
                vi[t][r] = aim[t][r] + lmi[t][r];
            }
    }

    // ---- loss = 1000 * sum_n min(0, 0.05 - |1 - |v||) per column ----
    float ls = 0.0f;
    #pragma unroll
    for (int t = 0; t < 2; ++t)
        #pragma unroll
        for (int r = 0; r < 4; ++r) {
            int row = 32 * w + 16 * t + 4 * g + r;
            if (row < N_BUS) {
                float na = sqrtf(vr[t][r] * vr[t][r] + vi[t][r] * vi[t][r]);
                ls += fminf(0.0f, 0.05f - fabsf(1.0f - na));
            }
        }
    // reduce the 4 lane-groups sharing column slot cc within this wave
    ls += __shfl_xor(ls, 16);
    ls += __shfl_xor(ls, 32);
    // cc and cc+8 are duplicates: only cc<8 contributes; 4 waves cover 128 rows
    if (g == 0 && cc < COLS) atomicAdd(&lossred[cc], ls);
    __syncthreads();
    if (tid < COLS) out[b0 + tid] = 1000.0f * lossred[tid];
}

extern "C" void kernel_launch(void* const* d_in, const int* in_sizes, int n_in,
                              void* d_out, int out_size, void* d_ws, size_t ws_size,
                              hipStream_t stream) {
    const float*  action = (const float*)d_in[0];
    const float*  state  = (const float*)d_in[1];
    const float2* K      = (const float2*)d_in[2];
    const float2* Lp     = (const float2*)d_in[3];
    float*  out   = (float*)d_out;
    short8* frags = (short8*)d_ws;   // 4096 * 16 B = 64 KiB

    prep_frags<<<16, 256, 0, stream>>>(K, frags);
    vvl_main<<<BATCH / COLS, 256, 0, stream>>>(action, state, frags, Lp, out);
}

// Round 15
// 14.632 us; speedup vs baseline: 1.4298x; 1.4298x over previous
//
#include <hip/hip_runtime.h>
#include <math.h>

#define N_BUS 127
#define BATCH 4096
#define NUM_CS 200
#define STATE_DIM 858   // 4 + 2*127 + 3*200
#define EV_START 258    // 4 + 2*127
#define COLS 16         // batch columns per block -> 256 blocks of 512 threads
#define NITER 2         // v2 err ~2e-6 <= bf16-K noise (~1e-4) << 0.03 margin

typedef __attribute__((ext_vector_type(8))) short short8;
typedef __attribute__((ext_vector_type(4))) short short4v;
typedef __attribute__((ext_vector_type(4))) float f32x4;

// RNE float -> bf16
static __device__ __forceinline__ short f2bf(float f) {
    unsigned u = __float_as_uint(f);
    return (short)((u + 0x7FFFu + ((u >> 16) & 1u)) >> 16);
}

// 8 waves x 512 threads. Wave w owns output rows [16w, 16w+16).
// MFMA 16x16x32 fragment roles (layout verified rounds 3-14):
//   A: row = 16w + (l&15), k = 32kt + 8*(l>>4) + i
//   B: col = l&15,         k = 32kt + 8*(l>>4) + i
//   D: col = l&15,         row = 16w + 4*(l>>4) + r
// Session ledger: kernel-side cost ~5 us; ~11 us is per-replay launch floor.
__global__ __launch_bounds__(512, 4) void vvl_main(const float* __restrict__ action,
                                                   const float* __restrict__ state,
                                                   const float2* __restrict__ K,
                                                   const float2* __restrict__ Lp,
                                                   float* __restrict__ out) {
    __shared__ float sq[COLS][258];      // [col]: p (EV added in) then q
    // B fragments, lane-linear: reader byte addr = const + 16*lane (conflict-free)
    __shared__ __align__(16) short B8s[2][2][4][4][COLS][8];
    __shared__ float lossred[COLS];

    const int tid = threadIdx.x;
    const int w  = tid >> 6;         // wave 0..7
    const int l  = tid & 63;
    const int cc = l & 15;           // batch column within tile
    const int g  = l >> 4;           // lane group 0..3
    const int b0 = blockIdx.x * COLS;
    const int col = tid >> 5;        // prologue column mapping (32 thr/col)
    const int j   = tid & 31;

    const float*  st_row_c = state + (size_t)(b0 + col) * STATE_DIM;
    const float2* st2      = (const float2*)(st_row_c + 4);
    const float*  act_row  = action + (size_t)(b0 + col) * NUM_CS;

    // ======= issue all prologue loads before any use (in-order VMEM) =======
    // batch 1: p/q (consumed first)
    float2 pqv[4];
    #pragma unroll
    for (int jj = 0; jj < 4; ++jj) {
        int idx = j + 32 * jj; idx = idx < 127 ? idx : 126;
        pqv[jj] = st2[idx];
    }
    // batch 2: EV (21 scalars)
    float av[7], capv[7], busv[7];
    #pragma unroll
    for (int kk = 0; kk < 7; ++kk) {
        int cs = j + 32 * kk; int csc = cs < NUM_CS ? cs : NUM_CS - 1;
        av[kk]   = act_row[csc];
        capv[kk] = st_row_c[EV_START + 3 * csc];
        busv[kk] = st_row_c[EV_START + 2 + 3 * csc];
    }
    // batch 3: K row-gather (L1 line reuse 8x within a lane)
    const int arow = 16 * w + (l & 15);
    const bool rok = arow < N_BUS;
    const float2* Krow = K + (size_t)(rok ? arow : 0) * N_BUS;
    float2 kv[32];
    #pragma unroll
    for (int kt = 0; kt < 4; ++kt)
        #pragma unroll
        for (int i = 0; i < 8; ++i) {
            int k = 32 * kt + 8 * g + i;
            kv[kt * 8 + i] = Krow[k < N_BUS ? k : 0];
        }
    // batch 4: Lp rows this lane owns (tiny, broadcast-cached)
    float2 lpv[4];
    #pragma unroll
    for (int r = 0; r < 4; ++r) {
        int row = 16 * w + 4 * g + r;
        lpv[r] = Lp[row < N_BUS ? row : 0];
    }

    if (tid < COLS) lossred[tid] = 0.0f;

    // ======= consume in issue order =======
    // pq -> LDS. NO barrier needed before the EV atomics: each column's pq
    // region is written and atomically updated by the SAME half-wave
    // (col = tid>>5 in both phases) -> intra-wave DS program order suffices.
    #pragma unroll
    for (int jj = 0; jj < 4; ++jj) {
        int idx = j + 32 * jj;
        if (idx < 127) *(float2*)&sq[col][2 * idx] = pqv[jj];
    }

    // EV power + scatter-add into staged p (waits batch 2; K in flight)
    #pragma unroll
    for (int kk = 0; kk < 7; ++kk) {
        int cs = j + 32 * kk;
        float cap  = capv[kk];
        float conn = (cap > 0.0f) ? 1.0f : 0.0f;
        float mch  = fminf(22.0f,  conn * (70.0f - cap) * 4.0f);  // /0.25 == *4
        float mds  = fmaxf(-22.0f, conn * (15.0f - cap) * 4.0f);
        float pw   = fmaxf(fminf(av[kk] * 22.17f, mch), mds);
        int bi = (int)busv[kk];
        bi = bi < 0 ? 0 : (bi > N_BUS - 1 ? N_BUS - 1 : bi);
        if (cs < NUM_CS) atomicAdd(&sq[col][bi], pw);
    }

    // convert K -> bf16 A-fragments (single wait on batch 3)
    short8 AKr[4], AKi[4];
    #pragma unroll
    for (int kt = 0; kt < 4; ++kt)
        #pragma unroll
        for (int i = 0; i < 8; ++i) {
            int k = 32 * kt + 8 * g + i;
            bool ok = rok && (k < N_BUS);
            float2 e = kv[kt * 8 + i];
            AKr[kt][i] = f2bf(ok ? e.x : 0.0f);
            AKi[kt][i] = f2bf(ok ? e.y : 0.0f);
        }

    __syncthreads();   // sq final (all columns' stores+atomics done)

    // ---- per-lane S/v state from LDS ----
    float Sr[4], Si[4], lmr[4], lmi[4], vr[4], vi[4];
    #pragma unroll
    for (int r = 0; r < 4; ++r) {
        int row = 16 * w + 4 * g + r;
        if (row < N_BUS) {
            Sr[r] = sq[cc][row] * 1e-3f;
            Si[r] = sq[cc][127 + row] * 1e-3f;
            lmr[r] = lpv[r].x; lmi[r] = lpv[r].y;
        } else {  // pad row 127: S=0 -> Lc=0; A col 127 is zero anyway
            Sr[r] = 0.0f; Si[r] = 0.0f; lmr[r] = 1.0f; lmi[r] = 0.0f;
        }
        vr[r] = 1.0f; vi[r] = 0.0f;
    }

    // writer-side B8 constants: this lane owns k = k0..k0+3 of column cc
    const int k0  = 16 * w + 4 * g;
    const int ktw = k0 >> 5;
    const int gi  = (k0 >> 3) & 3;
    const int i0  = k0 & 7;          // 0 or 4

    // ---- fixed-point loop: v = K @ conj(S/v) + L on matrix cores ----
    for (int it = 0; it < NITER; ++it) {
        const int buf = it & 1;
        short4v pr, pi;
        #pragma unroll
        for (int r = 0; r < 4; ++r) {
            float d   = vr[r] * vr[r] + vi[r] * vi[r];
            float inv = __builtin_amdgcn_rcpf(d);
            pr[r] = f2bf((Sr[r] * vr[r] + Si[r] * vi[r]) * inv);
            pi[r] = f2bf((Sr[r] * vi[r] - Si[r] * vr[r]) * inv);
        }
        *(short4v*)&B8s[buf][0][ktw][gi][cc][i0] = pr;
        *(short4v*)&B8s[buf][1][ktw][gi][cc][i0] = pi;
        __syncthreads();   // single barrier/iter; WAR safe via double buffer

        // Cre = Kr@Lr + Ki@(-Li) ; Cim = Kr@Li + Ki@Lr   (fp32 accum)
        f32x4 are = {0.f, 0.f, 0.f, 0.f}, aim = {0.f, 0.f, 0.f, 0.f};
        #pragma unroll
        for (int kt = 0; kt < 4; ++kt) {
            short8 Br  = *(const short8*)&B8s[buf][0][kt][g][cc][0];
            short8 Bi8 = *(const short8*)&B8s[buf][1][kt][g][cc][0];
            aim = __builtin_amdgcn_mfma_f32_16x16x32_bf16(AKr[kt], Bi8, aim, 0, 0, 0);
            aim = __builtin_amdgcn_mfma_f32_16x16x32_bf16(AKi[kt], Br,  aim, 0, 0, 0);
            are = __builtin_amdgcn_mfma_f32_16x16x32_bf16(AKr[kt], Br,  are, 0, 0, 0);
            #pragma unroll
            for (int i = 0; i < 8; ++i) Bi8[i] = Bi8[i] ^ (short)0x8000;   // -Li
            are = __builtin_amdgcn_mfma_f32_16x16x32_bf16(AKi[kt], Bi8, are, 0, 0, 0);
        }
        #pragma unroll
        for (int r = 0; r < 4; ++r) {
            vr[r] = are[r] + lmr[r];
            vi[r] = aim[r] + lmi[r];
        }
    }

    // ---- loss = 1000 * sum_n min(0, 0.05 - |1 - |v||) per column ----
    float ls = 0.0f;
    #pragma unroll
    for (int r = 0; r < 4; ++r) {
        int row = 16 * w + 4 * g + r;
        if (row < N_BUS) {
            float na = sqrtf(vr[r] * vr[r] + vi[r] * vi[r]);
            ls += fminf(0.0f, 0.05f - fabsf(1.0f - na));
        }
    }
    // reduce over the 4 lane-groups sharing column cc within this wave
    ls += __shfl_xor(ls, 16);
    ls += __shfl_xor(ls, 32);
    if (g == 0) atomicAdd(&lossred[cc], ls);   // 8 waves -> block total
    __syncthreads();
    if (tid < COLS) out[b0 + tid] = 1000.0f * lossred[tid];
}

extern "C" void kernel_launch(void* const* d_in, const int* in_sizes, int n_in,
                              void* d_out, int out_size, void* d_ws, size_t ws_size,
                              hipStream_t stream) {
    const float*  action = (const float*)d_in[0];
    const float*  state  = (const float*)d_in[1];
    const float2* K      = (const float2*)d_in[2];
    const float2* Lp     = (const float2*)d_in[3];
    float* out = (float*)d_out;

    vvl_main<<<BATCH / COLS, 512, 0, stream>>>(action, state, K, Lp, out);
}

// Round 18
// 14.621 us; speedup vs baseline: 1.4309x; 1.0008x over previous
//
#include <hip/hip_runtime.h>
#include <math.h>

#define N_BUS 127
#define BATCH 4096
#define NUM_CS 200
#define STATE_DIM 858   // 4 + 2*127 + 3*200
#define EV_START 258    // 4 + 2*127
#define COLS 16         // batch columns per block -> 256 blocks of 512 threads
#define NITER 2         // VALIDATED (r15, absmax 0.0). NITER=1 fails (r16/r17,
                        // identical absmax 84992 from two different impls) --
                        // the second iteration's contraction is load-bearing.

typedef __attribute__((ext_vector_type(8))) short short8;
typedef __attribute__((ext_vector_type(4))) short short4v;
typedef __attribute__((ext_vector_type(4))) float f32x4;

// RNE float -> bf16
static __device__ __forceinline__ short f2bf(float f) {
    unsigned u = __float_as_uint(f);
    return (short)((u + 0x7FFFu + ((u >> 16) & 1u)) >> 16);
}

// 8 waves x 512 threads. Wave w owns output rows [16w, 16w+16).
// MFMA 16x16x32 fragment roles (layout verified rounds 3-15):
//   A: row = 16w + (l&15), k = 32kt + 8*(l>>4) + i
//   B: col = l&15,         k = 32kt + 8*(l>>4) + i
//   D: col = l&15,         row = 16w + 4*(l>>4) + r
// Session ledger: kernel-side cost ~4 us; ~10-11 us is per-replay launch floor.
__global__ __launch_bounds__(512, 4) void vvl_main(const float* __restrict__ action,
                                                   const float* __restrict__ state,
                                                   const float2* __restrict__ K,
                                                   const float2* __restrict__ Lp,
                                                   float* __restrict__ out) {
    __shared__ float sq[COLS][258];      // [col]: p (EV added in) then q
    // B fragments, lane-linear: reader byte addr = const + 16*lane (conflict-free)
    __shared__ __align__(16) short B8s[2][2][4][4][COLS][8];
    __shared__ float lossred[COLS];

    const int tid = threadIdx.x;
    const int w  = tid >> 6;         // wave 0..7
    const int l  = tid & 63;
    const int cc = l & 15;           // batch column within tile
    const int g  = l >> 4;           // lane group 0..3
    const int b0 = blockIdx.x * COLS;
    const int col = tid >> 5;        // prologue column mapping (32 thr/col)
    const int j   = tid & 31;

    const float*  st_row_c = state + (size_t)(b0 + col) * STATE_DIM;
    const float2* st2      = (const float2*)(st_row_c + 4);
    const float*  act_row  = action + (size_t)(b0 + col) * NUM_CS;

    // ======= issue all prologue loads before any use (in-order VMEM) =======
    // batch 1: p/q (consumed first)
    float2 pqv[4];
    #pragma unroll
    for (int jj = 0; jj < 4; ++jj) {
        int idx = j + 32 * jj; idx = idx < 127 ? idx : 126;
        pqv[jj] = st2[idx];
    }
    // batch 2: EV (21 scalars)
    float av[7], capv[7], busv[7];
    #pragma unroll
    for (int kk = 0; kk < 7; ++kk) {
        int cs = j + 32 * kk; int csc = cs < NUM_CS ? cs : NUM_CS - 1;
        av[kk]   = act_row[csc];
        capv[kk] = st_row_c[EV_START + 3 * csc];
        busv[kk] = st_row_c[EV_START + 2 + 3 * csc];
    }
    // batch 3: K row-gather (L1 line reuse 8x within a lane)
    const int arow = 16 * w + (l & 15);
    const bool rok = arow < N_BUS;
    const float2* Krow = K + (size_t)(rok ? arow : 0) * N_BUS;
    float2 kv[32];
    #pragma unroll
    for (int kt = 0; kt < 4; ++kt)
        #pragma unroll
        for (int i = 0; i < 8; ++i) {
            int k = 32 * kt + 8 * g + i;
            kv[kt * 8 + i] = Krow[k < N_BUS ? k : 0];
        }
    // batch 4: Lp rows this lane owns (tiny, broadcast-cached)
    float2 lpv[4];
    #pragma unroll
    for (int r = 0; r < 4; ++r) {
        int row = 16 * w + 4 * g + r;
        lpv[r] = Lp[row < N_BUS ? row : 0];
    }

    if (tid < COLS) lossred[tid] = 0.0f;

    // ======= consume in issue order =======
    // pq -> LDS. No barrier before the EV atomics: each column's pq region is
    // written and atomically updated by the SAME half-wave (validated r15).
    #pragma unroll
    for (int jj = 0; jj < 4; ++jj) {
        int idx = j + 32 * jj;
        if (idx < 127) *(float2*)&sq[col][2 * idx] = pqv[jj];
    }

    // EV power + scatter-add into staged p (waits batch 2; K in flight)
    #pragma unroll
    for (int kk = 0; kk < 7; ++kk) {
        int cs = j + 32 * kk;
        float cap  = capv[kk];
        float conn = (cap > 0.0f) ? 1.0f : 0.0f;
        float mch  = fminf(22.0f,  conn * (70.0f - cap) * 4.0f);  // /0.25 == *4
        float mds  = fmaxf(-22.0f, conn * (15.0f - cap) * 4.0f);
        float pw   = fmaxf(fminf(av[kk] * 22.17f, mch), mds);
        int bi = (int)busv[kk];
        bi = bi < 0 ? 0 : (bi > N_BUS - 1 ? N_BUS - 1 : bi);
        if (cs < NUM_CS) atomicAdd(&sq[col][bi], pw);
    }

    // convert K -> bf16 A-fragments (single wait on batch 3)
    short8 AKr[4], AKi[4];
    #pragma unroll
    for (int kt = 0; kt < 4; ++kt)
        #pragma unroll
        for (int i = 0; i < 8; ++i) {
            int k = 32 * kt + 8 * g + i;
            bool ok = rok && (k < N_BUS);
            float2 e = kv[kt * 8 + i];
            AKr[kt][i] = f2bf(ok ? e.x : 0.0f);
            AKi[kt][i] = f2bf(ok ? e.y : 0.0f);
        }

    __syncthreads();   // sq final (all columns' stores+atomics done)

    // ---- per-lane S/v state from LDS ----
    float Sr[4], Si[4], lmr[4], lmi[4], vr[4], vi[4];
    #pragma unroll
    for (int r = 0; r < 4; ++r) {
        int row = 16 * w + 4 * g + r;
        if (row < N_BUS) {
            Sr[r] = sq[cc][row] * 1e-3f;
            Si[r] = sq[cc][127 + row] * 1e-3f;
            lmr[r] = lpv[r].x; lmi[r] = lpv[r].y;
        } else {  // pad row 127: S=0 -> Lc=0; A col 127 is zero anyway
            Sr[r] = 0.0f; Si[r] = 0.0f; lmr[r] = 1.0f; lmi[r] = 0.0f;
        }
        vr[r] = 1.0f; vi[r] = 0.0f;
    }

    // writer-side B8 constants: this lane owns k = k0..k0+3 of column cc
    const int k0  = 16 * w + 4 * g;
    const int ktw = k0 >> 5;
    const int gi  = (k0 >> 3) & 3;
    const int i0  = k0 & 7;          // 0 or 4

    // ---- fixed-point loop: v = K @ conj(S/v) + L on matrix cores ----
    for (int it = 0; it < NITER; ++it) {
        const int buf = it & 1;
        short4v pr, pi;
        #pragma unroll
        for (int r = 0; r < 4; ++r) {
            float d   = vr[r] * vr[r] + vi[r] * vi[r];
            float inv = __builtin_amdgcn_rcpf(d);
            pr[r] = f2bf((Sr[r] * vr[r] + Si[r] * vi[r]) * inv);
            pi[r] = f2bf((Sr[r] * vi[r] - Si[r] * vr[r]) * inv);
        }
        *(short4v*)&B8s[buf][0][ktw][gi][cc][i0] = pr;
        *(short4v*)&B8s[buf][1][ktw][gi][cc][i0] = pi;
        __syncthreads();   // single barrier/iter; WAR safe via double buffer

        // Cre = Kr@Lr + Ki@(-Li) ; Cim = Kr@Li + Ki@Lr   (fp32 accum)
        f32x4 are = {0.f, 0.f, 0.f, 0.f}, aim = {0.f, 0.f, 0.f, 0.f};
        #pragma unroll
        for (int kt = 0; kt < 4; ++kt) {
            short8 Br  = *(const short8*)&B8s[buf][0][kt][g][cc][0];
            short8 Bi8 = *(const short8*)&B8s[buf][1][kt][g][cc][0];
            aim = __builtin_amdgcn_mfma_f32_16x16x32_bf16(AKr[kt], Bi8, aim, 0, 0, 0);
            aim = __builtin_amdgcn_mfma_f32_16x16x32_bf16(AKi[kt], Br,  aim, 0, 0, 0);
            are = __builtin_amdgcn_mfma_f32_16x16x32_bf16(AKr[kt], Br,  are, 0, 0, 0);
            #pragma unroll
            for (int i = 0; i < 8; ++i) Bi8[i] = Bi8[i] ^ (short)0x8000;   // -Li
            are = __builtin_amdgcn_mfma_f32_16x16x32_bf16(AKi[kt], Bi8, are, 0, 0, 0);
        }
        #pragma unroll
        for (int r = 0; r < 4; ++r) {
            vr[r] = are[r] + lmr[r];
            vi[r] = aim[r] + lmi[r];
        }
    }

    // ---- loss = 1000 * sum_n min(0, 0.05 - |1 - |v||) per column ----
    float ls = 0.0f;
    #pragma unroll
    for (int r = 0; r < 4; ++r) {
        int row = 16 * w + 4 * g + r;
        if (row < N_BUS) {
            float na = sqrtf(vr[r] * vr[r] + vi[r] * vi[r]);
            ls += fminf(0.0f, 0.05f - fabsf(1.0f - na));
        }
    }
    // reduce over the 4 lane-groups sharing column cc within this wave
    ls += __shfl_xor(ls, 16);
    ls += __shfl_xor(ls, 32);
    if (g == 0) atomicAdd(&lossred[cc], ls);   // 8 waves -> block total
    __syncthreads();
    if (tid < COLS) out[b0 + tid] = 1000.0f * lossred[tid];
}

extern "C" void kernel_launch(void* const* d_in, const int* in_sizes, int n_in,
                              void* d_out, int out_size, void* d_ws, size_t ws_size,
                              hipStream_t stream) {
    const float*  action = (const float*)d_in[0];
    const float*  state  = (const float*)d_in[1];
    const float2* K      = (const float2*)d_in[2];
    const float2* Lp     = (const float2*)d_in[3];
    float* out = (float*)d_out;

    vvl_main<<<BATCH / COLS, 512, 0, stream>>>(action, state, K, Lp, out);
}